// Round 5
// baseline (177.836 us; speedup 1.0000x reference)
//
#include <hip/hip_runtime.h>
#include <hip/hip_fp16.h>
#include <hip/hip_cooperative_groups.h>
#include <math.h>

namespace cg = cooperative_groups;

#define NMODES 64
#define SDIM   1024
#define BATCH  256
#define PDIM   4096
#define HDIM   128
#define LDH    144

typedef _Float16 half8 __attribute__((ext_vector_type(8)));
typedef float f32x4 __attribute__((ext_vector_type(4)));

// ws layout (bytes):
//   branch @ 0     : f16 [256][128]    (64 KB)
//   t3     @ 65536 : f16 [4096][128]   (1 MB)
#define WSB_BRANCH 0
#define WSB_T3     (BATCH * HDIM * 2)

// LDS: phase-1 (trunk + fourier/branch) and phase-2 (MFMA tiles) overlap via
// union; 37.1 KB -> 4 blocks/CU capacity, cooperative needs only 1.
struct P1 {
    float h1L[16 * 132];
    float h2L[16 * 132];
    float featL[16][4];
    float ue[512];          // u0[s] + u0[1023-s]  (cos, even)
    float uo[512];          // u0[s] - u0[1023-s]  (sin, odd)
    float part[2][HDIM];
    float fr[HDIM];
    float hh[HDIM];
};
struct P2 {
    _Float16 brL[64 * LDH];
    _Float16 ttL[64 * LDH];
    float causL[64];
};
union SharedU { P1 p1; P2 p2; };

// ---------------------------------------------------------------------------
// Single cooperative kernel, 256 blocks x 256 threads.
//   Phase 1: block b -> trunk MLP for points 16b..16b+15 (t3, f16)
//            + fourier(symmetry-halved, hw-trans) + branch MLP for row b.
//   grid.sync()
//   Phase 2: block b -> 64x64 output tile (rb=b>>6, cb=b&63) via fp16 MFMA.
// ---------------------------------------------------------------------------
__global__ __launch_bounds__(256) void k_all(
    const float* __restrict__ u0,
    const float* __restrict__ xv, const float* __restrict__ tv,
    const float* __restrict__ bw1, const float* __restrict__ bb1,
    const float* __restrict__ bw2, const float* __restrict__ bb2,
    const float* __restrict__ bw3, const float* __restrict__ bb3,
    const float* __restrict__ tw1, const float* __restrict__ tb1,
    const float* __restrict__ tw2, const float* __restrict__ tb2,
    const float* __restrict__ tw3, const float* __restrict__ tb3,
    __half* __restrict__ branch_out, __half* __restrict__ t3g,
    float* __restrict__ out) {
    __shared__ SharedU sh;

    const int t = threadIdx.x;
    const int b = blockIdx.x;
    const int j = t & 127;
    const int pg = t >> 7;          // 0/1: point-group (trunk) / s-half (fourier)

    // ======================= Phase 1A: trunk MLP (16 points) ================
    {
        const int pbase = b * 16;
        if (t < 16) {
            int p = pbase + t;
            float x = xv[p], tt = tv[p];
            float q = tt * tt - x * x;
            float ptime = (q > 0.f) ? sqrtf(q) : 0.f;
            float c = (fabsf(x) <= tt) ? 1.f : 0.f;
            sh.p1.featL[t][0] = x; sh.p1.featL[t][1] = tt;
            sh.p1.featL[t][2] = ptime; sh.p1.featL[t][3] = c;
        }
        __syncthreads();

        // layer 1 (4 -> 128)
        {
            float4 w1 = ((const float4*)tw1)[j];
            float b1 = tb1[j];
            for (int p = pg; p < 16; p += 2) {
                float4 f = *(const float4*)sh.p1.featL[p];
                float v = fmaf(w1.x, f.x, fmaf(w1.y, f.y, fmaf(w1.z, f.z, fmaf(w1.w, f.w, b1))));
                sh.p1.h1L[p * 132 + j] = fmaxf(v, 0.f);
            }
        }
        __syncthreads();

        // layer 2 (128 -> 128, relu)
        {
            const float4* wp = (const float4*)(tw2 + (size_t)j * HDIM);
            float bias = tb2[j];
            float acc[8];
#pragma unroll
            for (int q = 0; q < 8; ++q) acc[q] = bias;
            for (int i4 = 0; i4 < 32; ++i4) {
                float4 wv = wp[i4];
#pragma unroll
                for (int q = 0; q < 8; ++q) {
                    float4 hv = *(const float4*)&sh.p1.h1L[(pg + q * 2) * 132 + i4 * 4];
                    acc[q] += wv.x * hv.x + wv.y * hv.y + wv.z * hv.z + wv.w * hv.w;
                }
            }
#pragma unroll
            for (int q = 0; q < 8; ++q) sh.p1.h2L[(pg + q * 2) * 132 + j] = fmaxf(acc[q], 0.f);
        }
        __syncthreads();

        // layer 3 (128 -> 128) -> f16 t3
        {
            const float4* wp = (const float4*)(tw3 + (size_t)j * HDIM);
            float bias = tb3[j];
            float acc[8];
#pragma unroll
            for (int q = 0; q < 8; ++q) acc[q] = bias;
            for (int i4 = 0; i4 < 32; ++i4) {
                float4 wv = wp[i4];
#pragma unroll
                for (int q = 0; q < 8; ++q) {
                    float4 hv = *(const float4*)&sh.p1.h2L[(pg + q * 2) * 132 + i4 * 4];
                    acc[q] += wv.x * hv.x + wv.y * hv.y + wv.z * hv.z + wv.w * hv.w;
                }
            }
#pragma unroll
            for (int q = 0; q < 8; ++q)
                t3g[(size_t)(pbase + pg + q * 2) * HDIM + j] = __float2half(acc[q]);
        }
    }
    __syncthreads();

    // ============ Phase 1B: fourier (symmetry-halved) + branch MLP ==========
    {
        // stage row b with even/odd combine: pairs (s, 1023-s)
        const float* up = u0 + (size_t)b * SDIM;
        for (int s = t; s < 512; s += 256) {
            float a = up[s];
            float c = up[1023 - s];
            sh.p1.ue[s] = a + c;
            sh.p1.uo[s] = a - c;
        }
        __syncthreads();

        // thread (j, pg): 256 s-values. angle in REVOLUTIONS:
        //   rev_s = 0.5*k*xs_s mod 1, xs_s = -1 + 2s/1023; step r = k/1023.
        {
            const int kmode = (j & 63) + 1;
            const int s_lo = pg * 256;
            float a = 0.5f * (float)kmode * (-1.0f + 2.0f * (float)s_lo / 1023.0f);
            a -= floorf(a);
            const float r = (float)kmode * (1.0f / 1023.0f);
            float acc = 0.f;
            if (j < 64) {   // wave-uniform branch (lanes 0..63 of wave share j-range)
#pragma unroll 8
                for (int s = s_lo; s < s_lo + 256; ++s) {
                    float bas = __builtin_amdgcn_cosf(a);
                    a += r; a -= floorf(a);
                    acc += bas * sh.p1.ue[s];   // wave-uniform LDS read -> broadcast
                }
            } else {
#pragma unroll 8
                for (int s = s_lo; s < s_lo + 256; ++s) {
                    float bas = __builtin_amdgcn_sinf(a);
                    a += r; a -= floorf(a);
                    acc += bas * sh.p1.uo[s];
                }
            }
            sh.p1.part[pg][j] = acc;
        }
        __syncthreads();
        if (t < 128)
            sh.p1.fr[j] = (sh.p1.part[0][j] + sh.p1.part[1][j]) * (1.0f / (float)SDIM);
        __syncthreads();

        // branch MLP, 1 row (t<128 active)
        float c0 = 0.f;
        if (t < 128) {
            const float4* wp = (const float4*)(bw1 + (size_t)j * HDIM);
            c0 = bb1[j];
            for (int i4 = 0; i4 < 32; ++i4) {
                float4 wv = wp[i4];
                float4 x0 = *(const float4*)&sh.p1.fr[i4 * 4];
                c0 += wv.x * x0.x + wv.y * x0.y + wv.z * x0.z + wv.w * x0.w;
            }
        }
        __syncthreads();
        if (t < 128) sh.p1.hh[j] = fmaxf(c0, 0.f);
        __syncthreads();
        if (t < 128) {
            const float4* wp = (const float4*)(bw2 + (size_t)j * HDIM);
            c0 = bb2[j];
            for (int i4 = 0; i4 < 32; ++i4) {
                float4 wv = wp[i4];
                float4 x0 = *(const float4*)&sh.p1.hh[i4 * 4];
                c0 += wv.x * x0.x + wv.y * x0.y + wv.z * x0.z + wv.w * x0.w;
            }
        }
        __syncthreads();
        if (t < 128) sh.p1.fr[j] = fmaxf(c0, 0.f);
        __syncthreads();
        if (t < 128) {
            const float4* wp = (const float4*)(bw3 + (size_t)j * HDIM);
            c0 = bb3[j];
            for (int i4 = 0; i4 < 32; ++i4) {
                float4 wv = wp[i4];
                float4 x0 = *(const float4*)&sh.p1.fr[i4 * 4];
                c0 += wv.x * x0.x + wv.y * x0.y + wv.z * x0.z + wv.w * x0.w;
            }
            branch_out[(size_t)b * HDIM + j] = __float2half(c0);
        }
    }

    // ======================= grid-wide barrier ==============================
    __threadfence();
    cg::this_grid().sync();

    // ======================= Phase 2: final MFMA tile =======================
    {
        const int rb = b >> 6;    // batch tile 0..3
        const int cb = b & 63;    // point tile 0..63

        if (t < 64) {
            int p = cb * 64 + t;
            float x = xv[p], tt = tv[p];
            sh.p2.causL[t] = (fabsf(x) <= tt) ? 1.f : 0.f;
        }

#pragma unroll
        for (int it = 0; it < 4; ++it) {
            int flat = t + 256 * it;
            int row = flat >> 4, c = flat & 15;
            *(float4*)&sh.p2.brL[row * LDH + c * 8] =
                *(const float4*)&branch_out[(size_t)(rb * 64 + row) * HDIM + c * 8];
            *(float4*)&sh.p2.ttL[row * LDH + c * 8] =
                *(const float4*)&t3g[(size_t)(cb * 64 + row) * HDIM + c * 8];
        }
        __syncthreads();

        const int lane = t & 63;
        const int w = t >> 6;
        const int lm = lane & 15;
        const int q = lane >> 4;

        f32x4 acc[4] = {f32x4{0,0,0,0}, f32x4{0,0,0,0}, f32x4{0,0,0,0}, f32x4{0,0,0,0}};

        const _Float16* aBase = &sh.p2.brL[(16 * w + lm) * LDH + q * 8];
#pragma unroll
        for (int ks = 0; ks < 4; ++ks) {
            half8 af = *(const half8*)(aBase + ks * 32);
#pragma unroll
            for (int jt = 0; jt < 4; ++jt) {
                half8 bf = *(const half8*)&sh.p2.ttL[(16 * jt + lm) * LDH + q * 8 + ks * 32];
                acc[jt] = __builtin_amdgcn_mfma_f32_16x16x32_f16(af, bf, acc[jt], 0, 0, 0);
            }
        }

        // C/D layout: col=lane&15, row=(lane>>4)*4+reg (m89-verified)
#pragma unroll
        for (int jt = 0; jt < 4; ++jt) {
            int col = cb * 64 + 16 * jt + lm;
            float cz = sh.p2.causL[16 * jt + lm];
#pragma unroll
            for (int e = 0; e < 4; ++e) {
                int row = rb * 64 + 16 * w + q * 4 + e;
                out[(size_t)row * PDIM + col] = acc[jt][e] * cz;
            }
        }
    }
}

// ---------------------------------------------------------------------------
extern "C" void kernel_launch(void* const* d_in, const int* in_sizes, int n_in,
                              void* d_out, int out_size, void* d_ws, size_t ws_size,
                              hipStream_t stream) {
    const float* u0  = (const float*)d_in[0];
    const float* xv  = (const float*)d_in[1];
    const float* tv  = (const float*)d_in[2];
    const float* bw1 = (const float*)d_in[3];
    const float* bb1 = (const float*)d_in[4];
    const float* bw2 = (const float*)d_in[5];
    const float* bb2 = (const float*)d_in[6];
    const float* bw3 = (const float*)d_in[7];
    const float* bb3 = (const float*)d_in[8];
    const float* tw1 = (const float*)d_in[9];
    const float* tb1 = (const float*)d_in[10];
    const float* tw2 = (const float*)d_in[11];
    const float* tb2 = (const float*)d_in[12];
    const float* tw3 = (const float*)d_in[13];
    const float* tb3 = (const float*)d_in[14];

    char* wsb = (char*)d_ws;
    __half* branch_out = (__half*)(wsb + WSB_BRANCH);
    __half* t3g        = (__half*)(wsb + WSB_T3);
    float* out = (float*)d_out;

    void* args[] = {
        (void*)&u0, (void*)&xv, (void*)&tv,
        (void*)&bw1, (void*)&bb1, (void*)&bw2, (void*)&bb2,
        (void*)&bw3, (void*)&bb3,
        (void*)&tw1, (void*)&tb1, (void*)&tw2, (void*)&tb2,
        (void*)&tw3, (void*)&tb3,
        (void*)&branch_out, (void*)&t3g, (void*)&out,
    };
    hipLaunchCooperativeKernel((const void*)k_all, dim3(256), dim3(256),
                               args, 0, stream);
}

// Round 6
// 108.565 us; speedup vs baseline: 1.6381x; 1.6381x over previous
//
#include <hip/hip_runtime.h>
#include <hip/hip_fp16.h>
#include <math.h>

#define NMODES 64
#define SDIM   1024
#define BATCH  256
#define PDIM   4096
#define HDIM   128

typedef _Float16 half8 __attribute__((ext_vector_type(8)));
typedef float f32x4 __attribute__((ext_vector_type(4)));

// ws layout (bytes):
//   branch @ 0     : f16 [256][128]    (64 KB)
//   t3     @ 65536 : f16 [4096][128]   (1 MB)
#define WSB_BRANCH 0
#define WSB_T3     (BATCH * HDIM * 2)

// ---------------------------------------------------------------------------
// K1 (fused, 384 blocks):
//   blocks 0..255   : trunk MLP, 16 points each -> t3 (f16)
//   blocks 256..383 : fourier (symmetry-halved, hw-trans) + branch MLP, 2 rows
// Trunk layers 2/3 use a 2-unit x 4-point register block: LDS reads are
// wave-uniform broadcasts, halved vs 1x8 mapping; summation order per output
// is unchanged (i4 ascending) -> bit-identical numerics.
// ---------------------------------------------------------------------------
__global__ __launch_bounds__(256) void k_fused(
    const float* __restrict__ u0,
    const float* __restrict__ xv, const float* __restrict__ tv,
    const float* __restrict__ bw1, const float* __restrict__ bb1,
    const float* __restrict__ bw2, const float* __restrict__ bb2,
    const float* __restrict__ bw3, const float* __restrict__ bb3,
    const float* __restrict__ tw1, const float* __restrict__ tb1,
    const float* __restrict__ tw2, const float* __restrict__ tb2,
    const float* __restrict__ tw3, const float* __restrict__ tb3,
    __half* __restrict__ branch_out, __half* __restrict__ t3g) {
    __shared__ float h1L[16 * 132];
    __shared__ float h2L[16 * 132];
    __shared__ float featL[16][4];
    __shared__ float ue[2][512];        // u0[s]+u0[1023-s] per row (cos/even)
    __shared__ float uo[2][512];        // u0[s]-u0[1023-s] per row (sin/odd)
    __shared__ float part[2][2][HDIM];
    __shared__ float fr[2][HDIM];
    __shared__ float hh[2][HDIM];

    const int t = threadIdx.x;

    if (blockIdx.x < 256) {
        // ================= trunk MLP (16 points) =================
        const int pbase = blockIdx.x * 16;
        const int j = t & 127;
        const int pg = t >> 7;

        if (t < 16) {
            int p = pbase + t;
            float x = xv[p], tt = tv[p];
            float q = tt * tt - x * x;
            float ptime = (q > 0.f) ? sqrtf(q) : 0.f;
            float c = (fabsf(x) <= tt) ? 1.f : 0.f;
            featL[t][0] = x; featL[t][1] = tt; featL[t][2] = ptime; featL[t][3] = c;
        }
        __syncthreads();

        // layer 1 (4 -> 128)
        {
            float4 w1 = ((const float4*)tw1)[j];
            float b1 = tb1[j];
            for (int p = pg; p < 16; p += 2) {
                float4 f = *(const float4*)featL[p];
                float v = fmaf(w1.x, f.x, fmaf(w1.y, f.y, fmaf(w1.z, f.z, fmaf(w1.w, f.w, b1))));
                h1L[p * 132 + j] = fmaxf(v, 0.f);
            }
        }
        __syncthreads();

        // layers 2/3: thread = (u2 = t&63 -> units {u2, u2+64}, pq = t>>6 ->
        // points {pq, pq+4, pq+8, pq+12}).
        const int u2 = t & 63;
        const int pq = t >> 6;

        // layer 2 (128 -> 128, relu)
        {
            const float4* wpA = (const float4*)(tw2 + (size_t)u2 * HDIM);
            const float4* wpB = (const float4*)(tw2 + (size_t)(u2 + 64) * HDIM);
            float accA[4], accB[4];
            float ba = tb2[u2], bbv = tb2[u2 + 64];
#pragma unroll
            for (int n = 0; n < 4; ++n) { accA[n] = ba; accB[n] = bbv; }
            for (int i4 = 0; i4 < 32; ++i4) {
                float4 wa = wpA[i4];
                float4 wb = wpB[i4];
#pragma unroll
                for (int n = 0; n < 4; ++n) {
                    float4 x4 = *(const float4*)&h1L[(pq + 4 * n) * 132 + i4 * 4];
                    accA[n] += wa.x * x4.x + wa.y * x4.y + wa.z * x4.z + wa.w * x4.w;
                    accB[n] += wb.x * x4.x + wb.y * x4.y + wb.z * x4.z + wb.w * x4.w;
                }
            }
#pragma unroll
            for (int n = 0; n < 4; ++n) {
                h2L[(pq + 4 * n) * 132 + u2]      = fmaxf(accA[n], 0.f);
                h2L[(pq + 4 * n) * 132 + u2 + 64] = fmaxf(accB[n], 0.f);
            }
        }
        __syncthreads();

        // layer 3 (128 -> 128) -> f16 t3
        {
            const float4* wpA = (const float4*)(tw3 + (size_t)u2 * HDIM);
            const float4* wpB = (const float4*)(tw3 + (size_t)(u2 + 64) * HDIM);
            float accA[4], accB[4];
            float ba = tb3[u2], bbv = tb3[u2 + 64];
#pragma unroll
            for (int n = 0; n < 4; ++n) { accA[n] = ba; accB[n] = bbv; }
            for (int i4 = 0; i4 < 32; ++i4) {
                float4 wa = wpA[i4];
                float4 wb = wpB[i4];
#pragma unroll
                for (int n = 0; n < 4; ++n) {
                    float4 x4 = *(const float4*)&h2L[(pq + 4 * n) * 132 + i4 * 4];
                    accA[n] += wa.x * x4.x + wa.y * x4.y + wa.z * x4.z + wa.w * x4.w;
                    accB[n] += wb.x * x4.x + wb.y * x4.y + wb.z * x4.z + wb.w * x4.w;
                }
            }
#pragma unroll
            for (int n = 0; n < 4; ++n) {
                size_t row = (size_t)(pbase + pq + 4 * n) * HDIM;
                t3g[row + u2]      = __float2half(accA[n]);
                t3g[row + u2 + 64] = __float2half(accB[n]);
            }
        }
        return;
    }

    // ============ fourier (symmetry-halved) + branch MLP (2 rows) ==========
    const int bb = (blockIdx.x - 256) * 2;
    const int j = t & 127;
    const int half = t >> 7;

    // stage 2 rows with even/odd combine over pairs (s, 1023-s)
    {
        const float* u0p = u0 + (size_t)bb * SDIM;
        const float* u1p = u0p + SDIM;
        for (int s = t; s < 512; s += 256) {
            float a0 = u0p[s], c0 = u0p[1023 - s];
            float a1 = u1p[s], c1 = u1p[1023 - s];
            ue[0][s] = a0 + c0; uo[0][s] = a0 - c0;
            ue[1][s] = a1 + c1; uo[1][s] = a1 - c1;
        }
    }
    __syncthreads();

    // thread (j, half): 256 s-values. angle in REVOLUTIONS:
    //   rev_s = 0.5*k*xs_s mod 1, xs_s = -1 + 2s/1023; step r = k/1023.
    // One basis eval feeds both rows (bas reused).
    {
        const int kmode = (j & 63) + 1;
        const int s_lo = half * 256;
        float a = 0.5f * (float)kmode * (-1.0f + 2.0f * (float)s_lo / 1023.0f);
        a -= floorf(a);
        const float r = (float)kmode * (1.0f / 1023.0f);
        float a0 = 0.f, a1 = 0.f;
        if (j < 64) {   // wave-uniform branch
#pragma unroll 8
            for (int s = s_lo; s < s_lo + 256; ++s) {
                float bas = __builtin_amdgcn_cosf(a);
                a += r; a -= floorf(a);
                a0 += bas * ue[0][s];
                a1 += bas * ue[1][s];
            }
        } else {
#pragma unroll 8
            for (int s = s_lo; s < s_lo + 256; ++s) {
                float bas = __builtin_amdgcn_sinf(a);
                a += r; a -= floorf(a);
                a0 += bas * uo[0][s];
                a1 += bas * uo[1][s];
            }
        }
        part[half][0][j] = a0;
        part[half][1][j] = a1;
    }
    __syncthreads();
    if (t < 128) {
        const float sc = 1.0f / (float)SDIM;
        fr[0][j] = (part[0][0][j] + part[1][0][j]) * sc;
        fr[1][j] = (part[0][1][j] + part[1][1][j]) * sc;
    }
    __syncthreads();

    if (t < 128) {
        // layer 1
        {
            const float4* wp = (const float4*)(bw1 + (size_t)j * HDIM);
            float c0 = bb1[j], c1 = c0;
            for (int i4 = 0; i4 < 32; ++i4) {
                float4 wv = wp[i4];
                float4 x0 = *(const float4*)&fr[0][i4 * 4];
                float4 x1 = *(const float4*)&fr[1][i4 * 4];
                c0 += wv.x * x0.x + wv.y * x0.y + wv.z * x0.z + wv.w * x0.w;
                c1 += wv.x * x1.x + wv.y * x1.y + wv.z * x1.z + wv.w * x1.w;
            }
            hh[0][j] = fmaxf(c0, 0.f); hh[1][j] = fmaxf(c1, 0.f);
        }
        __syncthreads();
        // layer 2
        {
            const float4* wp = (const float4*)(bw2 + (size_t)j * HDIM);
            float c0 = bb2[j], c1 = c0;
            for (int i4 = 0; i4 < 32; ++i4) {
                float4 wv = wp[i4];
                float4 x0 = *(const float4*)&hh[0][i4 * 4];
                float4 x1 = *(const float4*)&hh[1][i4 * 4];
                c0 += wv.x * x0.x + wv.y * x0.y + wv.z * x0.z + wv.w * x0.w;
                c1 += wv.x * x1.x + wv.y * x1.y + wv.z * x1.z + wv.w * x1.w;
            }
            fr[0][j] = fmaxf(c0, 0.f); fr[1][j] = fmaxf(c1, 0.f);
        }
        __syncthreads();
        // layer 3 -> f16 branch
        {
            const float4* wp = (const float4*)(bw3 + (size_t)j * HDIM);
            float c0 = bb3[j], c1 = c0;
            for (int i4 = 0; i4 < 32; ++i4) {
                float4 wv = wp[i4];
                float4 x0 = *(const float4*)&fr[0][i4 * 4];
                float4 x1 = *(const float4*)&fr[1][i4 * 4];
                c0 += wv.x * x0.x + wv.y * x0.y + wv.z * x0.z + wv.w * x0.w;
                c1 += wv.x * x1.x + wv.y * x1.y + wv.z * x1.z + wv.w * x1.w;
            }
            branch_out[(size_t)(bb + 0) * HDIM + j] = __float2half(c0);
            branch_out[(size_t)(bb + 1) * HDIM + j] = __float2half(c1);
        }
    } else {
        __syncthreads();
        __syncthreads();
    }
}

// ---------------------------------------------------------------------------
// K2: final einsum via fp16 MFMA. out(256x4096) = br(256x128) @ t3^T * causal.
// 256 blocks (4 batch-tiles x 64 point-tiles of 64x64).
// ---------------------------------------------------------------------------
#define LDH 144
__global__ __launch_bounds__(256) void k_final(
    const __half* __restrict__ br_g, const __half* __restrict__ t3g,
    const float* __restrict__ xv, const float* __restrict__ tv,
    float* __restrict__ out) {
    __shared__ _Float16 brL[64 * LDH];
    __shared__ _Float16 ttL[64 * LDH];
    __shared__ float causL[64];

    const int t = threadIdx.x;
    const int rb = blockIdx.x >> 6;   // batch tile 0..3
    const int cb = blockIdx.x & 63;   // point tile 0..63

    if (t < 64) {
        int p = cb * 64 + t;
        float x = xv[p], tt = tv[p];
        causL[t] = (fabsf(x) <= tt) ? 1.f : 0.f;
    }

#pragma unroll
    for (int it = 0; it < 4; ++it) {
        int flat = t + 256 * it;
        int row = flat >> 4, c = flat & 15;
        *(float4*)&brL[row * LDH + c * 8] =
            *(const float4*)&br_g[(size_t)(rb * 64 + row) * HDIM + c * 8];
        *(float4*)&ttL[row * LDH + c * 8] =
            *(const float4*)&t3g[(size_t)(cb * 64 + row) * HDIM + c * 8];
    }
    __syncthreads();

    const int lane = t & 63;
    const int w = t >> 6;
    const int lm = lane & 15;
    const int q = lane >> 4;

    f32x4 acc[4] = {f32x4{0,0,0,0}, f32x4{0,0,0,0}, f32x4{0,0,0,0}, f32x4{0,0,0,0}};

    const _Float16* aBase = &brL[(16 * w + lm) * LDH + q * 8];
#pragma unroll
    for (int ks = 0; ks < 4; ++ks) {
        half8 af = *(const half8*)(aBase + ks * 32);
#pragma unroll
        for (int jt = 0; jt < 4; ++jt) {
            half8 bf = *(const half8*)&ttL[(16 * jt + lm) * LDH + q * 8 + ks * 32];
            acc[jt] = __builtin_amdgcn_mfma_f32_16x16x32_f16(af, bf, acc[jt], 0, 0, 0);
        }
    }

    // C/D layout: col=lane&15, row=(lane>>4)*4+reg (m89-verified)
#pragma unroll
    for (int jt = 0; jt < 4; ++jt) {
        int col = cb * 64 + 16 * jt + lm;
        float cz = causL[16 * jt + lm];
#pragma unroll
        for (int e = 0; e < 4; ++e) {
            int row = rb * 64 + 16 * w + q * 4 + e;
            out[(size_t)row * PDIM + col] = acc[jt][e] * cz;
        }
    }
}

// ---------------------------------------------------------------------------
extern "C" void kernel_launch(void* const* d_in, const int* in_sizes, int n_in,
                              void* d_out, int out_size, void* d_ws, size_t ws_size,
                              hipStream_t stream) {
    const float* u0  = (const float*)d_in[0];
    const float* xv  = (const float*)d_in[1];
    const float* tv  = (const float*)d_in[2];
    const float* bw1 = (const float*)d_in[3];
    const float* bb1 = (const float*)d_in[4];
    const float* bw2 = (const float*)d_in[5];
    const float* bb2 = (const float*)d_in[6];
    const float* bw3 = (const float*)d_in[7];
    const float* bb3 = (const float*)d_in[8];
    const float* tw1 = (const float*)d_in[9];
    const float* tb1 = (const float*)d_in[10];
    const float* tw2 = (const float*)d_in[11];
    const float* tb2 = (const float*)d_in[12];
    const float* tw3 = (const float*)d_in[13];
    const float* tb3 = (const float*)d_in[14];

    char* wsb = (char*)d_ws;
    __half* branch_out = (__half*)(wsb + WSB_BRANCH);
    __half* t3g        = (__half*)(wsb + WSB_T3);
    float* out = (float*)d_out;

    hipLaunchKernelGGL(k_fused, dim3(384), dim3(256), 0, stream,
                       u0, xv, tv, bw1, bb1, bw2, bb2, bw3, bb3,
                       tw1, tb1, tw2, tb2, tw3, tb3, branch_out, t3g);
    hipLaunchKernelGGL(k_final, dim3(256), dim3(256), 0, stream,
                       branch_out, t3g, xv, tv, out);
}